// Round 1
// 670.918 us; speedup vs baseline: 1.2040x; 1.2040x over previous
//
#include <hip/hip_runtime.h>
#include <hip/hip_bf16.h>
#include <math.h>

#define NFEAT 512
#define HID   64
#define NCLS  40

#define BSHIFT 9
#define BSIZE  512              // nodes per bucket
#define BCAP   20480            // staged edges per bucket (avg ~16.3K, sd ~128)
#define CHUNK  4096             // edges per bin_scatter block

struct __align__(8) bf16x4 { __hip_bfloat16 a, b, c, d; };

// ---------------- CSR build: two-level binning ----------------

__global__ __launch_bounds__(256) void bin_scatter(const int* __restrict__ ei, int e,
                                                   int nbuckets,
                                                   int* __restrict__ bucket_cursor,
                                                   int* __restrict__ stage) {
    __shared__ int packed_s[CHUNK];
    __shared__ unsigned char bkt_s[CHUNK];
    __shared__ int hist[256];
    __shared__ int base_s[256];
    __shared__ int lcur[256];
    int t = threadIdx.x;
    int b0 = blockIdx.x * CHUNK;
    int cnt = min(CHUNK, e - b0);
    for (int i = t; i < 256; i += 256) hist[i] = 0;
    __syncthreads();
    for (int i = t; i < cnt; i += 256) {
        int s = ei[b0 + i];
        int d = ei[e + b0 + i];
        packed_s[i] = (s << BSHIFT) | (d & (BSIZE - 1));
        bkt_s[i] = (unsigned char)(d >> BSHIFT);
        atomicAdd(&hist[d >> BSHIFT], 1);
    }
    __syncthreads();
    for (int i = t; i < nbuckets; i += 256) {
        int c = hist[i];
        base_s[i] = c ? atomicAdd(&bucket_cursor[i], c) : 0;
        lcur[i] = 0;
    }
    __syncthreads();
    for (int i = t; i < cnt; i += 256) {
        int bk = bkt_s[i];
        int pos = base_s[bk] + atomicAdd(&lcur[bk], 1);
        if (pos < BCAP) stage[(size_t)bk * BCAP + pos] = packed_s[i];
    }
}

__global__ __launch_bounds__(256) void bucket_scan(const int* __restrict__ bucket_cursor,
                                                   int* __restrict__ bucket_base,
                                                   int nbuckets, int n, int e,
                                                   int* __restrict__ row_ptr) {
    __shared__ int sc[256];
    int t = threadIdx.x;
    int v = (t < nbuckets) ? bucket_cursor[t] : 0;
    sc[t] = v;
    __syncthreads();
    #pragma unroll
    for (int off = 1; off < 256; off <<= 1) {
        int u = (t >= off) ? sc[t - off] : 0;
        __syncthreads();
        sc[t] += u;
        __syncthreads();
    }
    if (t < nbuckets) bucket_base[t] = sc[t] - v;
    if (t == 0) row_ptr[n] = e;
}

__global__ __launch_bounds__(256) void bucket_csr(const int* __restrict__ stage,
                                                  const int* __restrict__ bucket_cursor,
                                                  const int* __restrict__ bucket_base,
                                                  int* __restrict__ row_ptr,
                                                  float* __restrict__ dinv,
                                                  int* __restrict__ col, int n) {
    __shared__ int hist[BSIZE];
    __shared__ int lbase[BSIZE];
    __shared__ int psum[256];
    int b = blockIdx.x;
    int t = threadIdx.x;
    int cnt = min(bucket_cursor[b], BCAP);
    int node0 = b << BSHIFT;
    int nnodes = min(BSIZE, n - node0);
    const int* st = stage + (size_t)b * BCAP;
    for (int i = t; i < BSIZE; i += 256) hist[i] = 0;
    __syncthreads();
    for (int i = t; i < cnt; i += 256) atomicAdd(&hist[st[i] & (BSIZE - 1)], 1);
    __syncthreads();
    int h0 = hist[2 * t], h1 = hist[2 * t + 1];
    int pair = h0 + h1;
    psum[t] = pair;
    __syncthreads();
    #pragma unroll
    for (int off = 1; off < 256; off <<= 1) {
        int u = (t >= off) ? psum[t - off] : 0;
        __syncthreads();
        psum[t] += u;
        __syncthreads();
    }
    int ex = psum[t] - pair;
    lbase[2 * t] = ex;
    lbase[2 * t + 1] = ex + h0;
    __syncthreads();
    int base0 = bucket_base[b];
    for (int i = t; i < nnodes; i += 256) {
        row_ptr[node0 + i] = base0 + lbase[i];
        dinv[node0 + i] = rsqrtf((float)(hist[i] + 1));
    }
    __syncthreads();
    for (int i = t; i < cnt; i += 256) {
        int p = st[i];
        int pos = atomicAdd(&lbase[p & (BSIZE - 1)], 1);
        col[base0 + pos] = ((unsigned)p) >> BSHIFT;
    }
}

// ---------------- GEMM1: t1 = bf16( dinv[:,None] * (x @ W1) ) ----------------

__global__ __launch_bounds__(256) void gemm1(const float* __restrict__ x,
                                             const float* __restrict__ W1,
                                             const float* __restrict__ dinv,
                                             __hip_bfloat16* __restrict__ t1, int n) {
    __shared__ __align__(16) float xst[32][68];
    __shared__ __align__(16) float wsh[32][64];
    int m0 = blockIdx.x * 64;
    int t = threadIdx.x;
    int tr = t >> 4;
    int tc = t & 15;
    float acc[4][4] = {};

    for (int k0 = 0; k0 < NFEAT; k0 += 32) {
        #pragma unroll
        for (int s = 0; s < 2; s++) {
            int slot = t + s * 256;
            int row = slot >> 3;
            int kv  = slot & 7;
            int grow = m0 + row;
            if (grow >= n) grow = n - 1;
            float4 v = *(const float4*)(x + (size_t)grow * NFEAT + k0 + kv * 4);
            xst[kv * 4 + 0][row] = v.x;
            xst[kv * 4 + 1][row] = v.y;
            xst[kv * 4 + 2][row] = v.z;
            xst[kv * 4 + 3][row] = v.w;
        }
        #pragma unroll
        for (int s = 0; s < 2; s++) {
            int slot = t + s * 256;
            int kr = slot >> 4;
            int cv = slot & 15;
            float4 v = *(const float4*)(W1 + (size_t)(k0 + kr) * HID + cv * 4);
            *(float4*)(&wsh[kr][cv * 4]) = v;
        }
        __syncthreads();
        #pragma unroll
        for (int k = 0; k < 32; k++) {
            float4 a = *(const float4*)(&xst[k][tr * 4]);
            float4 b = *(const float4*)(&wsh[k][tc * 4]);
            acc[0][0] += a.x * b.x; acc[0][1] += a.x * b.y; acc[0][2] += a.x * b.z; acc[0][3] += a.x * b.w;
            acc[1][0] += a.y * b.x; acc[1][1] += a.y * b.y; acc[1][2] += a.y * b.z; acc[1][3] += a.y * b.w;
            acc[2][0] += a.z * b.x; acc[2][1] += a.z * b.y; acc[2][2] += a.z * b.z; acc[2][3] += a.z * b.w;
            acc[3][0] += a.w * b.x; acc[3][1] += a.w * b.y; acc[3][2] += a.w * b.z; acc[3][3] += a.w * b.w;
        }
        __syncthreads();
    }
    #pragma unroll
    for (int i = 0; i < 4; i++) {
        int row = m0 + tr * 4 + i;
        if (row < n) {
            float d = dinv[row];
            bf16x4 o;
            o.a = __float2bfloat16(acc[i][0] * d);
            o.b = __float2bfloat16(acc[i][1] * d);
            o.c = __float2bfloat16(acc[i][2] * d);
            o.d = __float2bfloat16(acc[i][3] * d);
            *(bf16x4*)(t1 + (size_t)row * HID + tc * 4) = o;
        }
    }
}

// ---------------- fused agg1 + gemm2:  t2 = bf16( dinv*( relu(dinv*agg(t1)+b1) @ W2 ) ) ----------------
// Gather restructured for MLP: 2 edges per load instruction (dword = 2 bf16 feats/lane,
// lanes 0-31 = edge A row, lanes 32-63 = edge B row), software-pipelined 8 loads deep
// => 16 edges (2 KB) in flight per wave vs 2 edges (256 B) before.

__global__ __launch_bounds__(256) void agg1_gemm2(const __hip_bfloat16* __restrict__ t1,
                                                  const int* __restrict__ row_ptr,
                                                  const int* __restrict__ col,
                                                  const float* __restrict__ dinv,
                                                  const float* __restrict__ b1,
                                                  const float* __restrict__ W2,
                                                  __hip_bfloat16* __restrict__ t2, int n) {
    __shared__ float w2s[64 * 41];
    for (int i = threadIdx.x; i < 64 * 40; i += 256) w2s[i] = W2[i];
    __syncthreads();
    int wave = threadIdx.x >> 6;
    int lane = threadIdx.x & 63;
    int node = blockIdx.x * 4 + wave;
    if (node >= n) return;
    int q = lane & 31;          // feature pair: feats {2q, 2q+1}
    int h = lane >> 5;          // which edge of the pair this half-wave handles
    int s0 = row_ptr[node], s1 = row_ptr[node + 1];

    const unsigned int* t1u = (const unsigned int*)t1;   // row stride = 32 dwords
    float accx = 0.0f, accy = 0.0f;
    if (h == 0) {  // self loop counted once (halves are summed at the end)
        unsigned int pv = t1u[(size_t)node * 32 + q];
        accx = __uint_as_float(pv << 16);
        accy = __uint_as_float(pv & 0xffff0000u);
    }
    int j = s0;
    // main: 16 edges per iteration, 8 dword-gathers in flight
    for (; j + 16 <= s1; j += 16) {
        int cvec = col[j + (lane & 15)];
        int ci[8];
        #pragma unroll
        for (int i = 0; i < 8; i++) {
            int ca = __shfl(cvec, 2 * i, 64);      // readlane (uniform idx)
            int cb = __shfl(cvec, 2 * i + 1, 64);
            ci[i] = h ? cb : ca;
        }
        unsigned int pv[8];
        #pragma unroll
        for (int i = 0; i < 8; i++) pv[i] = t1u[(size_t)ci[i] * 32 + q];
        #pragma unroll
        for (int i = 0; i < 8; i++) {
            accx += __uint_as_float(pv[i] << 16);
            accy += __uint_as_float(pv[i] & 0xffff0000u);
        }
    }
    // 2-edge steps
    for (; j + 2 <= s1; j += 2) {
        int c2 = col[j + h];
        unsigned int pv = t1u[(size_t)c2 * 32 + q];
        accx += __uint_as_float(pv << 16);
        accy += __uint_as_float(pv & 0xffff0000u);
    }
    // odd tail: half 0 only
    if (j < s1 && h == 0) {
        int c1 = col[j];
        unsigned int pv = t1u[(size_t)c1 * 32 + q];
        accx += __uint_as_float(pv << 16);
        accy += __uint_as_float(pv & 0xffff0000u);
    }
    // merge the two edge-halves
    accx += __shfl_xor(accx, 32, 64);
    accy += __shfl_xor(accy, 32, 64);

    float dn = dinv[node];
    float2 bv = *(const float2*)(b1 + 2 * q);
    float hx = fmaxf(0.0f, dn * accx + bv.x);
    float hy = fmaxf(0.0f, dn * accy + bv.y);

    int c = (lane < 40) ? lane : 39;
    float o = 0.0f;
    #pragma unroll
    for (int k = 0; k < 32; k++) {
        float sx = __shfl(hx, k, 64);   // readlane
        float sy = __shfl(hy, k, 64);
        o += sx * w2s[(2 * k) * 40 + c] + sy * w2s[(2 * k + 1) * 40 + c];
    }
    if (lane < 40) t2[(size_t)node * NCLS + lane] = __float2bfloat16(dn * o);
}

// ---------------- agg2 + bias + softmax ----------------
// Same MLP fix: depth-8 software-pipelined gathers (640 B in flight/wave vs 160 B).

__global__ __launch_bounds__(256) void agg2_softmax(const __hip_bfloat16* __restrict__ t2,
                                                    const int* __restrict__ row_ptr,
                                                    const int* __restrict__ col,
                                                    const float* __restrict__ dinv,
                                                    const float* __restrict__ b2,
                                                    float* __restrict__ out, int n) {
    int wave = threadIdx.x >> 6;
    int lane = threadIdx.x & 63;
    int node = blockIdx.x * 4 + wave;
    if (node >= n) return;
    int c = (lane < 40) ? lane : 39;
    int s0 = row_ptr[node], s1 = row_ptr[node + 1];
    const unsigned short* t2u = (const unsigned short*)t2;
    float acc = __uint_as_float(((unsigned)t2u[(size_t)node * NCLS + c]) << 16);  // self
    int j = s0;
    for (; j + 8 <= s1; j += 8) {
        int cv = col[j + (lane & 7)];
        int ci[8];
        #pragma unroll
        for (int i = 0; i < 8; i++) ci[i] = __shfl(cv, i, 64);  // readlane
        unsigned short pv[8];
        #pragma unroll
        for (int i = 0; i < 8; i++) pv[i] = t2u[(size_t)ci[i] * NCLS + c];
        #pragma unroll
        for (int i = 0; i < 8; i++) acc += __uint_as_float(((unsigned)pv[i]) << 16);
    }
    for (; j < s1; j++) {
        acc += __uint_as_float(((unsigned)t2u[(size_t)col[j] * NCLS + c]) << 16);
    }
    float logit = dinv[node] * acc + b2[c];
    float m = (lane < 40) ? logit : -INFINITY;
    #pragma unroll
    for (int off = 32; off; off >>= 1) m = fmaxf(m, __shfl_xor(m, off, 64));
    float e = (lane < 40) ? expf(logit - m) : 0.0f;
    float ssum = e;
    #pragma unroll
    for (int off = 32; off; off >>= 1) ssum += __shfl_xor(ssum, off, 64);
    if (lane < 40) out[(size_t)node * NCLS + lane] = e / ssum;
}

// ---------------- launch ----------------

static inline size_t align256(size_t x) { return (x + 255) & ~(size_t)255; }

extern "C" void kernel_launch(void* const* d_in, const int* in_sizes, int n_in,
                              void* d_out, int out_size, void* d_ws, size_t ws_size,
                              hipStream_t stream) {
    const float* x  = (const float*)d_in[0];
    const int*   ei = (const int*)d_in[1];
    const float* W1 = (const float*)d_in[2];
    const float* b1 = (const float*)d_in[3];
    const float* W2 = (const float*)d_in[4];
    const float* b2 = (const float*)d_in[5];
    float* out = (float*)d_out;

    const int n = in_sizes[0] / NFEAT;      // 100000
    const int e = in_sizes[1] / 2;          // 3200000
    const int nbuckets = (n + BSIZE - 1) >> BSHIFT;   // 196

    char* ws = (char*)d_ws;
    size_t off = 0;
    int*   row_ptr  = (int*)(ws + off);   off += align256((size_t)(n + 1) * 4);
    float* dinv     = (float*)(ws + off); off += align256((size_t)n * 4);
    int*   bcursor  = (int*)(ws + off);   off += align256(256 * 4);
    int*   bbase    = (int*)(ws + off);   off += align256(256 * 4);
    int*   col      = (int*)(ws + off);   off += align256((size_t)e * 4);
    int*   stage    = (int*)(ws + off);   off += align256((size_t)nbuckets * BCAP * 4);
    __hip_bfloat16* t1 = (__hip_bfloat16*)(ws + off); off += align256((size_t)n * HID * 2);
    __hip_bfloat16* t2 = (__hip_bfloat16*)(ws + off); off += align256((size_t)n * NCLS * 2);

    (void)hipMemsetAsync(bcursor, 0, 256 * 4, stream);
    bin_scatter<<<(e + CHUNK - 1) / CHUNK, 256, 0, stream>>>(ei, e, nbuckets, bcursor, stage);
    bucket_scan<<<1, 256, 0, stream>>>(bcursor, bbase, nbuckets, n, e, row_ptr);
    bucket_csr<<<nbuckets, 256, 0, stream>>>(stage, bcursor, bbase, row_ptr, dinv, col, n);
    gemm1<<<(n + 63) / 64, 256, 0, stream>>>(x, W1, dinv, t1, n);
    agg1_gemm2<<<(n + 3) / 4, 256, 0, stream>>>(t1, row_ptr, col, dinv, b1, W2, t2, n);
    agg2_softmax<<<(n + 3) / 4, 256, 0, stream>>>(t2, row_ptr, col, dinv, b2, out, n);
}

// Round 2
// 562.492 us; speedup vs baseline: 1.4361x; 1.1928x over previous
//
#include <hip/hip_runtime.h>
#include <hip/hip_bf16.h>
#include <math.h>

#define NFEAT 512
#define HID   64
#define NCLS  40

#define BSHIFT 9
#define BSIZE  512              // nodes per bucket
#define BCAP   20480            // staged edges per bucket (avg ~16.3K, sd ~128)
#define CHUNK  4096             // edges per bin_scatter block

struct __align__(8) bf16x4 { __hip_bfloat16 a, b, c, d; };

__device__ __forceinline__ float rl_f(float v, int l) {
    return __int_as_float(__builtin_amdgcn_readlane(__float_as_int(v), l));
}

// ---------------- CSR build: two-level binning ----------------

__global__ __launch_bounds__(256) void bin_scatter(const int* __restrict__ ei, int e,
                                                   int nbuckets,
                                                   int* __restrict__ bucket_cursor,
                                                   int* __restrict__ stage) {
    __shared__ int packed_s[CHUNK];
    __shared__ unsigned char bkt_s[CHUNK];
    __shared__ int hist[256];
    __shared__ int base_s[256];
    __shared__ int lcur[256];
    int t = threadIdx.x;
    int b0 = blockIdx.x * CHUNK;
    int cnt = min(CHUNK, e - b0);
    for (int i = t; i < 256; i += 256) hist[i] = 0;
    __syncthreads();
    for (int i = t; i < cnt; i += 256) {
        int s = ei[b0 + i];
        int d = ei[e + b0 + i];
        packed_s[i] = (s << BSHIFT) | (d & (BSIZE - 1));
        bkt_s[i] = (unsigned char)(d >> BSHIFT);
        atomicAdd(&hist[d >> BSHIFT], 1);
    }
    __syncthreads();
    for (int i = t; i < nbuckets; i += 256) {
        int c = hist[i];
        base_s[i] = c ? atomicAdd(&bucket_cursor[i], c) : 0;
        lcur[i] = 0;
    }
    __syncthreads();
    for (int i = t; i < cnt; i += 256) {
        int bk = bkt_s[i];
        int pos = base_s[bk] + atomicAdd(&lcur[bk], 1);
        if (pos < BCAP) stage[(size_t)bk * BCAP + pos] = packed_s[i];
    }
}

__global__ __launch_bounds__(256) void bucket_scan(const int* __restrict__ bucket_cursor,
                                                   int* __restrict__ bucket_base,
                                                   int nbuckets, int n, int e,
                                                   int* __restrict__ row_ptr) {
    __shared__ int sc[256];
    int t = threadIdx.x;
    int v = (t < nbuckets) ? bucket_cursor[t] : 0;
    sc[t] = v;
    __syncthreads();
    #pragma unroll
    for (int off = 1; off < 256; off <<= 1) {
        int u = (t >= off) ? sc[t - off] : 0;
        __syncthreads();
        sc[t] += u;
        __syncthreads();
    }
    if (t < nbuckets) bucket_base[t] = sc[t] - v;
    if (t == 0) row_ptr[n] = e;
}

__global__ __launch_bounds__(256) void bucket_csr(const int* __restrict__ stage,
                                                  const int* __restrict__ bucket_cursor,
                                                  const int* __restrict__ bucket_base,
                                                  int* __restrict__ row_ptr,
                                                  float* __restrict__ dinv,
                                                  int* __restrict__ col, int n) {
    __shared__ int hist[BSIZE];
    __shared__ int lbase[BSIZE];
    __shared__ int psum[256];
    int b = blockIdx.x;
    int t = threadIdx.x;
    int cnt = min(bucket_cursor[b], BCAP);
    int node0 = b << BSHIFT;
    int nnodes = min(BSIZE, n - node0);
    const int* st = stage + (size_t)b * BCAP;
    for (int i = t; i < BSIZE; i += 256) hist[i] = 0;
    __syncthreads();
    for (int i = t; i < cnt; i += 256) atomicAdd(&hist[st[i] & (BSIZE - 1)], 1);
    __syncthreads();
    int h0 = hist[2 * t], h1 = hist[2 * t + 1];
    int pair = h0 + h1;
    psum[t] = pair;
    __syncthreads();
    #pragma unroll
    for (int off = 1; off < 256; off <<= 1) {
        int u = (t >= off) ? psum[t - off] : 0;
        __syncthreads();
        psum[t] += u;
        __syncthreads();
    }
    int ex = psum[t] - pair;
    lbase[2 * t] = ex;
    lbase[2 * t + 1] = ex + h0;
    __syncthreads();
    int base0 = bucket_base[b];
    for (int i = t; i < nnodes; i += 256) {
        row_ptr[node0 + i] = base0 + lbase[i];
        dinv[node0 + i] = rsqrtf((float)(hist[i] + 1));
    }
    __syncthreads();
    for (int i = t; i < cnt; i += 256) {
        int p = st[i];
        int pos = atomicAdd(&lbase[p & (BSIZE - 1)], 1);
        col[base0 + pos] = ((unsigned)p) >> BSHIFT;
    }
}

// ---------------- GEMM1: t1 = bf16( dinv[:,None] * (x @ W1) ) ----------------

__global__ __launch_bounds__(256) void gemm1(const float* __restrict__ x,
                                             const float* __restrict__ W1,
                                             const float* __restrict__ dinv,
                                             __hip_bfloat16* __restrict__ t1, int n) {
    __shared__ __align__(16) float xst[32][68];
    __shared__ __align__(16) float wsh[32][64];
    int m0 = blockIdx.x * 64;
    int t = threadIdx.x;
    int tr = t >> 4;
    int tc = t & 15;
    float acc[4][4] = {};

    for (int k0 = 0; k0 < NFEAT; k0 += 32) {
        #pragma unroll
        for (int s = 0; s < 2; s++) {
            int slot = t + s * 256;
            int row = slot >> 3;
            int kv  = slot & 7;
            int grow = m0 + row;
            if (grow >= n) grow = n - 1;
            float4 v = *(const float4*)(x + (size_t)grow * NFEAT + k0 + kv * 4);
            xst[kv * 4 + 0][row] = v.x;
            xst[kv * 4 + 1][row] = v.y;
            xst[kv * 4 + 2][row] = v.z;
            xst[kv * 4 + 3][row] = v.w;
        }
        #pragma unroll
        for (int s = 0; s < 2; s++) {
            int slot = t + s * 256;
            int kr = slot >> 4;
            int cv = slot & 15;
            float4 v = *(const float4*)(W1 + (size_t)(k0 + kr) * HID + cv * 4);
            *(float4*)(&wsh[kr][cv * 4]) = v;
        }
        __syncthreads();
        #pragma unroll
        for (int k = 0; k < 32; k++) {
            float4 a = *(const float4*)(&xst[k][tr * 4]);
            float4 b = *(const float4*)(&wsh[k][tc * 4]);
            acc[0][0] += a.x * b.x; acc[0][1] += a.x * b.y; acc[0][2] += a.x * b.z; acc[0][3] += a.x * b.w;
            acc[1][0] += a.y * b.x; acc[1][1] += a.y * b.y; acc[1][2] += a.y * b.z; acc[1][3] += a.y * b.w;
            acc[2][0] += a.z * b.x; acc[2][1] += a.z * b.y; acc[2][2] += a.z * b.z; acc[2][3] += a.z * b.w;
            acc[3][0] += a.w * b.x; acc[3][1] += a.w * b.y; acc[3][2] += a.w * b.z; acc[3][3] += a.w * b.w;
        }
        __syncthreads();
    }
    #pragma unroll
    for (int i = 0; i < 4; i++) {
        int row = m0 + tr * 4 + i;
        if (row < n) {
            float d = dinv[row];
            bf16x4 o;
            o.a = __float2bfloat16(acc[i][0] * d);
            o.b = __float2bfloat16(acc[i][1] * d);
            o.c = __float2bfloat16(acc[i][2] * d);
            o.d = __float2bfloat16(acc[i][3] * d);
            *(bf16x4*)(t1 + (size_t)row * HID + tc * 4) = o;
        }
    }
}

// ---------------- fused agg1 + gemm2 ----------------
// Gather: 8 lanes per 128B row (dwordx4 per lane) -> 8 edges per VMEM instruction,
// depth-4 pipeline (32 edges/batch, 1KB in flight). Per-lane src index via one
// ds_bpermute per instruction. Tail handled branchlessly via zero sentinel row t1[n].
// GEMM2: h stays in registers (butterfly cross-slot reduce), broadcast via
// v_readlane (VALU pipe, not DS); W2 read as float2 k-pairs -> 32 DS ops/node
// (was 128 DS ops/node: the round-1 DS-pipe bottleneck).

#define UNPACK_ADD(pv) do { \
    acc[0] += __uint_as_float((pv).x << 16); acc[1] += __uint_as_float((pv).x & 0xffff0000u); \
    acc[2] += __uint_as_float((pv).y << 16); acc[3] += __uint_as_float((pv).y & 0xffff0000u); \
    acc[4] += __uint_as_float((pv).z << 16); acc[5] += __uint_as_float((pv).z & 0xffff0000u); \
    acc[6] += __uint_as_float((pv).w << 16); acc[7] += __uint_as_float((pv).w & 0xffff0000u); } while (0)

__global__ __launch_bounds__(256) void agg1_gemm2(const __hip_bfloat16* __restrict__ t1,
                                                  const int* __restrict__ row_ptr,
                                                  const int* __restrict__ col,
                                                  const float* __restrict__ dinv,
                                                  const float* __restrict__ b1,
                                                  const float* __restrict__ W2,
                                                  __hip_bfloat16* __restrict__ t2, int n) {
    __shared__ float2 w2p[32 * 40];   // [k/2][c] float2 = {W2[2k'][c], W2[2k'+1][c]}
    for (int i = threadIdx.x; i < 32 * 40; i += 256) {
        int k2 = i / 40, c = i - k2 * 40;
        w2p[i] = make_float2(W2[(2 * k2) * 40 + c], W2[(2 * k2 + 1) * 40 + c]);
    }
    __syncthreads();

    int wave = threadIdx.x >> 6;
    int lane = threadIdx.x & 63;
    int node0 = blockIdx.x * 4 + wave;
    int node = (node0 < n) ? node0 : n - 1;   // clamp; store masked at end
    int r = lane & 7;                          // 16B chunk within row (feats 8r..8r+7)
    int slot = lane >> 3;                      // edge slot within 8-edge group

    const uint4* t1q = (const uint4*)t1;       // row = 8 uint4
    int s0 = row_ptr[node], s1 = row_ptr[node + 1];

    float acc[8] = {0.f, 0.f, 0.f, 0.f, 0.f, 0.f, 0.f, 0.f};

    // self loop: slot 0 only (r == lane for lane < 8)
    if (lane < 8) {
        uint4 pv = t1q[(size_t)node * 8 + lane];
        UNPACK_ADD(pv);
    }

    int bpbase = slot * 4;                     // bpermute byte index base
    for (int jb = s0; jb < s1; jb += 32) {
        int rem = s1 - jb;
        int ll = lane & 31;
        int cidx = col[jb + ((ll < rem) ? ll : 0)];
        int srcg[4];
        #pragma unroll
        for (int g = 0; g < 4; g++) {
            int src = __builtin_amdgcn_ds_bpermute(bpbase + 32 * g, cidx);
            srcg[g] = (8 * g + slot < rem) ? src : n;   // sentinel -> zero row
        }
        uint4 pv[4];
        #pragma unroll
        for (int g = 0; g < 4; g++) pv[g] = t1q[(size_t)srcg[g] * 8 + r];
        #pragma unroll
        for (int g = 0; g < 4; g++) { UNPACK_ADD(pv[g]); }
    }

    // cross-slot butterfly: after this every lane holds full sums for feats 8r..8r+7
    #pragma unroll
    for (int off = 8; off < 64; off <<= 1) {
        #pragma unroll
        for (int j = 0; j < 8; j++) acc[j] += __shfl_xor(acc[j], off, 64);
    }

    float dn = dinv[node];
    const float4* b1q = (const float4*)b1;
    float4 ba = b1q[2 * r];
    float4 bb = b1q[2 * r + 1];
    float hv[8];
    hv[0] = fmaxf(0.f, dn * acc[0] + ba.x);
    hv[1] = fmaxf(0.f, dn * acc[1] + ba.y);
    hv[2] = fmaxf(0.f, dn * acc[2] + ba.z);
    hv[3] = fmaxf(0.f, dn * acc[3] + ba.w);
    hv[4] = fmaxf(0.f, dn * acc[4] + bb.x);
    hv[5] = fmaxf(0.f, dn * acc[5] + bb.y);
    hv[6] = fmaxf(0.f, dn * acc[6] + bb.z);
    hv[7] = fmaxf(0.f, dn * acc[7] + bb.w);

    int c = (lane < 40) ? lane : 39;
    float o = 0.0f;
    #pragma unroll
    for (int rr = 0; rr < 8; rr++) {
        #pragma unroll
        for (int j2 = 0; j2 < 4; j2++) {
            float ha = rl_f(hv[2 * j2],     rr);   // h[8rr + 2j2]   (lane rr holds it)
            float hb = rl_f(hv[2 * j2 + 1], rr);   // h[8rr + 2j2+1]
            float2 w = w2p[(4 * rr + j2) * 40 + c];
            o += ha * w.x + hb * w.y;
        }
    }
    if (node0 < n && lane < 40) t2[(size_t)node * NCLS + lane] = __float2bfloat16(dn * o);
}

// ---------------- agg2 + bias + softmax ----------------
// 2 edges per VMEM instruction: dword = 2 classes per lane; lanes 0-19 edge A,
// lanes 32-51 edge B. Depth-8 pipeline (16 edges in flight). Sentinel zero row t2[n].

__global__ __launch_bounds__(256) void agg2_softmax(const __hip_bfloat16* __restrict__ t2,
                                                    const int* __restrict__ row_ptr,
                                                    const int* __restrict__ col,
                                                    const float* __restrict__ dinv,
                                                    const float* __restrict__ b2,
                                                    float* __restrict__ out, int n) {
    int wave = threadIdx.x >> 6;
    int lane = threadIdx.x & 63;
    int node = blockIdx.x * 4 + wave;
    if (node >= n) return;
    int h = lane >> 5;                 // which edge of the pair
    int p = lane & 31;                 // class-pair index
    int pc = (p < 20) ? p : 19;        // clamped (lanes 20-31 are dead weight)
    const unsigned* t2d = (const unsigned*)t2;   // row = 20 dwords
    int s0 = row_ptr[node], s1 = row_ptr[node + 1];

    float ax = 0.f, ay = 0.f;
    if (h == 0) {                      // self loop counted once
        unsigned v = t2d[(size_t)node * 20 + pc];
        ax = __uint_as_float(v << 16);
        ay = __uint_as_float(v & 0xffff0000u);
    }
    for (int jb = s0; jb < s1; jb += 16) {
        int rem = s1 - jb;
        int cv = col[jb + ((lane < rem) ? lane : 0)];
        int srcg[8];
        #pragma unroll
        for (int i = 0; i < 8; i++) {
            int eid = 2 * i + h;
            int src = __builtin_amdgcn_ds_bpermute(4 * eid, cv);
            srcg[i] = (eid < rem) ? src : n;           // sentinel -> zero row
        }
        unsigned pv[8];
        #pragma unroll
        for (int i = 0; i < 8; i++) pv[i] = t2d[(size_t)srcg[i] * 20 + pc];
        #pragma unroll
        for (int i = 0; i < 8; i++) {
            ax += __uint_as_float(pv[i] << 16);
            ay += __uint_as_float(pv[i] & 0xffff0000u);
        }
    }
    // merge edge halves
    ax += __shfl_xor(ax, 32, 64);
    ay += __shfl_xor(ay, 32, 64);

    float dn = dinv[node];
    float2 bv = *(const float2*)(b2 + 2 * pc);
    float lx = dn * ax + bv.x;
    float ly = dn * ay + bv.y;
    float m = (p < 20) ? fmaxf(lx, ly) : -INFINITY;
    #pragma unroll
    for (int off = 16; off; off >>= 1) m = fmaxf(m, __shfl_xor(m, off, 64));
    float ex = (p < 20) ? expf(lx - m) : 0.0f;
    float ey = (p < 20) ? expf(ly - m) : 0.0f;
    float ssum = ex + ey;
    #pragma unroll
    for (int off = 16; off; off >>= 1) ssum += __shfl_xor(ssum, off, 64);
    if (h == 0 && p < 20) {
        *(float2*)(out + (size_t)node * NCLS + 2 * p) = make_float2(ex / ssum, ey / ssum);
    }
}

// ---------------- launch ----------------

static inline size_t align256(size_t x) { return (x + 255) & ~(size_t)255; }

extern "C" void kernel_launch(void* const* d_in, const int* in_sizes, int n_in,
                              void* d_out, int out_size, void* d_ws, size_t ws_size,
                              hipStream_t stream) {
    const float* x  = (const float*)d_in[0];
    const int*   ei = (const int*)d_in[1];
    const float* W1 = (const float*)d_in[2];
    const float* b1 = (const float*)d_in[3];
    const float* W2 = (const float*)d_in[4];
    const float* b2 = (const float*)d_in[5];
    float* out = (float*)d_out;

    const int n = in_sizes[0] / NFEAT;      // 100000
    const int e = in_sizes[1] / 2;          // 3200000
    const int nbuckets = (n + BSIZE - 1) >> BSHIFT;   // 196

    char* ws = (char*)d_ws;
    size_t off = 0;
    int*   row_ptr  = (int*)(ws + off);   off += align256((size_t)(n + 1) * 4);
    float* dinv     = (float*)(ws + off); off += align256((size_t)n * 4);
    int*   bcursor  = (int*)(ws + off);   off += align256(256 * 4);
    int*   bbase    = (int*)(ws + off);   off += align256(256 * 4);
    int*   col      = (int*)(ws + off);   off += align256((size_t)e * 4);
    int*   stage    = (int*)(ws + off);   off += align256((size_t)nbuckets * BCAP * 4);
    __hip_bfloat16* t1 = (__hip_bfloat16*)(ws + off); off += align256((size_t)(n + 1) * HID * 2);
    __hip_bfloat16* t2 = (__hip_bfloat16*)(ws + off); off += align256((size_t)(n + 1) * NCLS * 2);

    (void)hipMemsetAsync(bcursor, 0, 256 * 4, stream);
    (void)hipMemsetAsync(t1 + (size_t)n * HID, 0, HID * 2, stream);    // sentinel zero row
    (void)hipMemsetAsync(t2 + (size_t)n * NCLS, 0, NCLS * 2, stream);  // sentinel zero row
    bin_scatter<<<(e + CHUNK - 1) / CHUNK, 256, 0, stream>>>(ei, e, nbuckets, bcursor, stage);
    bucket_scan<<<1, 256, 0, stream>>>(bcursor, bbase, nbuckets, n, e, row_ptr);
    bucket_csr<<<nbuckets, 256, 0, stream>>>(stage, bcursor, bbase, row_ptr, dinv, col, n);
    gemm1<<<(n + 63) / 64, 256, 0, stream>>>(x, W1, dinv, t1, n);
    agg1_gemm2<<<(n + 3) / 4, 256, 0, stream>>>(t1, row_ptr, col, dinv, b1, W2, t2, n);
    agg2_softmax<<<(n + 3) / 4, 256, 0, stream>>>(t2, row_ptr, col, dinv, b2, out, n);
}

// Round 3
// 550.814 us; speedup vs baseline: 1.4665x; 1.0212x over previous
//
#include <hip/hip_runtime.h>
#include <hip/hip_bf16.h>
#include <math.h>

#define NFEAT 512
#define HID   64
#define NCLS  40
#define T2STRIDE 64             // t2 rows padded to 128B (one cache line)

#define BSHIFT 9
#define BSIZE  512              // nodes per bucket
#define BCAP   20480            // staged edges per bucket (avg ~16.3K, sd ~128)
#define CHUNK  4096             // edges per bin_scatter block

typedef __attribute__((ext_vector_type(8))) short bf16x8v;   // 8 bf16 = 4 VGPR
typedef __attribute__((ext_vector_type(4))) float f32x4v;    // MFMA acc

__device__ __forceinline__ float rl_f(float v, int l) {
    return __int_as_float(__builtin_amdgcn_readlane(__float_as_int(v), l));
}
__device__ __forceinline__ unsigned short f2bf(float f) {
    __hip_bfloat16 h = __float2bfloat16(f);
    return *(unsigned short*)&h;
}

// ---------------- CSR build: two-level binning ----------------

__global__ __launch_bounds__(256) void bin_scatter(const int* __restrict__ ei, int e,
                                                   int nbuckets,
                                                   int* __restrict__ bucket_cursor,
                                                   int* __restrict__ stage) {
    __shared__ int packed_s[CHUNK];
    __shared__ unsigned char bkt_s[CHUNK];
    __shared__ int hist[256];
    __shared__ int base_s[256];
    __shared__ int lcur[256];
    int t = threadIdx.x;
    int b0 = blockIdx.x * CHUNK;
    int cnt = min(CHUNK, e - b0);
    for (int i = t; i < 256; i += 256) hist[i] = 0;
    __syncthreads();
    for (int i = t; i < cnt; i += 256) {
        int s = ei[b0 + i];
        int d = ei[e + b0 + i];
        packed_s[i] = (s << BSHIFT) | (d & (BSIZE - 1));
        bkt_s[i] = (unsigned char)(d >> BSHIFT);
        atomicAdd(&hist[d >> BSHIFT], 1);
    }
    __syncthreads();
    for (int i = t; i < nbuckets; i += 256) {
        int c = hist[i];
        base_s[i] = c ? atomicAdd(&bucket_cursor[i], c) : 0;
        lcur[i] = 0;
    }
    __syncthreads();
    for (int i = t; i < cnt; i += 256) {
        int bk = bkt_s[i];
        int pos = base_s[bk] + atomicAdd(&lcur[bk], 1);
        if (pos < BCAP) stage[(size_t)bk * BCAP + pos] = packed_s[i];
    }
}

// bucket_csr with the bucket-base scan folded in (each block redundantly scans
// the 196 cursors in LDS -- removes the bucket_scan launch + dependency bubble)
__global__ __launch_bounds__(256) void bucket_csr(const int* __restrict__ stage,
                                                  const int* __restrict__ bucket_cursor,
                                                  int* __restrict__ row_ptr,
                                                  float* __restrict__ dinv,
                                                  int* __restrict__ col,
                                                  int n, int e, int nbuckets) {
    __shared__ int sc[256];
    __shared__ int hist[BSIZE];
    __shared__ int lbase[BSIZE];
    __shared__ int psum[256];
    int b = blockIdx.x;
    int t = threadIdx.x;
    // inclusive scan of bucket_cursor
    int v = (t < nbuckets) ? bucket_cursor[t] : 0;
    sc[t] = v;
    __syncthreads();
    #pragma unroll
    for (int off = 1; off < 256; off <<= 1) {
        int u = (t >= off) ? sc[t - off] : 0;
        __syncthreads();
        sc[t] += u;
        __syncthreads();
    }
    int base0 = (b > 0) ? sc[b - 1] : 0;
    if (b == 0 && t == 0) row_ptr[n] = e;

    int cnt = min(bucket_cursor[b], BCAP);
    int node0 = b << BSHIFT;
    int nnodes = min(BSIZE, n - node0);
    const int* st = stage + (size_t)b * BCAP;
    for (int i = t; i < BSIZE; i += 256) hist[i] = 0;
    __syncthreads();
    for (int i = t; i < cnt; i += 256) atomicAdd(&hist[st[i] & (BSIZE - 1)], 1);
    __syncthreads();
    int h0 = hist[2 * t], h1 = hist[2 * t + 1];
    int pair = h0 + h1;
    psum[t] = pair;
    __syncthreads();
    #pragma unroll
    for (int off = 1; off < 256; off <<= 1) {
        int u = (t >= off) ? psum[t - off] : 0;
        __syncthreads();
        psum[t] += u;
        __syncthreads();
    }
    int ex = psum[t] - pair;
    lbase[2 * t] = ex;
    lbase[2 * t + 1] = ex + h0;
    __syncthreads();
    for (int i = t; i < nnodes; i += 256) {
        row_ptr[node0 + i] = base0 + lbase[i];
        dinv[node0 + i] = rsqrtf((float)(hist[i] + 1));
    }
    __syncthreads();
    for (int i = t; i < cnt; i += 256) {
        int p = st[i];
        int pos = atomicAdd(&lbase[p & (BSIZE - 1)], 1);
        col[base0 + pos] = ((unsigned)p) >> BSHIFT;
    }
}

// ---------------- one-time: W1 -> bf16, transposed [64][512] ----------------

__global__ __launch_bounds__(256) void w1_to_bf16t(const float* __restrict__ W1,
                                                   unsigned short* __restrict__ w1bt) {
    int idx = blockIdx.x * 256 + threadIdx.x;   // 64*512 = 32768
    int c = idx >> 9, k = idx & 511;
    w1bt[idx] = f2bf(W1[k * HID + c]);
}

// ---------------- GEMM1 (MFMA): t1 = bf16( dinv[:,None] * (x @ W1) ) ----------------
// Round-2 version was LDS-BW bound (~6.5 GB LDS traffic @ 69 TB/s ~= 95 us).
// MFMA cuts LDS traffic ~10x; new floor is the 205 MB x-read (~35 us).
// Fragment layout (m89/m91-verified): A row=lane&15, k=8*(lane>>4)+j;
// B col=lane&15, same k; C/D col=lane&15, row=4*(lane>>4)+reg.

__global__ __launch_bounds__(256) void gemm1(const float* __restrict__ x,
                                             const unsigned short* __restrict__ w1bt,
                                             const float* __restrict__ dinv,
                                             __hip_bfloat16* __restrict__ t1, int n) {
    __shared__ __align__(16) unsigned short As[64][40];  // [row][k], pad 40 (bank-spread)
    __shared__ __align__(16) unsigned short Bs[64][40];  // [col][k], pad 40
    int t = threadIdx.x;
    int m0 = blockIdx.x * 64;
    int w = t >> 6, lane = t & 63;
    int lrow = lane & 15, lkg = lane >> 4;
    f32x4v acc[4] = {};

    int arow = t >> 2;        // staging row / col (0..63)
    int akg = t & 3;          // k-group of 8
    int grow = m0 + arow; if (grow >= n) grow = n - 1;
    const float* xrow = x + (size_t)grow * NFEAT;

    for (int k0 = 0; k0 < NFEAT; k0 += 32) {
        // stage A: 8 f32 -> 8 bf16 (coalesced 128B per 4 threads)
        float4 v0 = *(const float4*)(xrow + k0 + akg * 8);
        float4 v1 = *(const float4*)(xrow + k0 + akg * 8 + 4);
        union { unsigned short u[8]; uint4 q; } P;
        P.u[0] = f2bf(v0.x); P.u[1] = f2bf(v0.y); P.u[2] = f2bf(v0.z); P.u[3] = f2bf(v0.w);
        P.u[4] = f2bf(v1.x); P.u[5] = f2bf(v1.y); P.u[6] = f2bf(v1.z); P.u[7] = f2bf(v1.w);
        *(uint4*)&As[arow][akg * 8] = P.q;
        // stage B: already bf16-transposed, 16B copy
        *(uint4*)&Bs[arow][akg * 8] = *(const uint4*)(w1bt + arow * 512 + k0 + akg * 8);
        __syncthreads();
        bf16x8v af = *(const bf16x8v*)&As[w * 16 + lrow][lkg * 8];
        #pragma unroll
        for (int nb = 0; nb < 4; nb++) {
            bf16x8v bfv = *(const bf16x8v*)&Bs[nb * 16 + lrow][lkg * 8];
            acc[nb] = __builtin_amdgcn_mfma_f32_16x16x32_bf16(af, bfv, acc[nb], 0, 0, 0);
        }
        __syncthreads();
    }
    #pragma unroll
    for (int r = 0; r < 4; r++) {
        int row = m0 + w * 16 + lkg * 4 + r;
        if (row < n) {
            float d = dinv[row];
            #pragma unroll
            for (int nb = 0; nb < 4; nb++) {
                t1[(size_t)row * HID + nb * 16 + lrow] = __float2bfloat16(acc[nb][r] * d);
            }
        }
    }
}

// ---------------- fused agg1 + gemm2 ----------------
// 8 lanes per 128B row (dwordx4/lane) -> 8 edges per VMEM instruction, depth-4
// (32 edges, 4KB in flight/wave). ds_bpermute index broadcast; zero sentinel row t1[n].
// GEMM2 via v_readlane broadcasts (VALU, not DS) + 32 LDS float2 reads/node.

#define UNPACK_ADD(pv) do { \
    acc[0] += __uint_as_float((pv).x << 16); acc[1] += __uint_as_float((pv).x & 0xffff0000u); \
    acc[2] += __uint_as_float((pv).y << 16); acc[3] += __uint_as_float((pv).y & 0xffff0000u); \
    acc[4] += __uint_as_float((pv).z << 16); acc[5] += __uint_as_float((pv).z & 0xffff0000u); \
    acc[6] += __uint_as_float((pv).w << 16); acc[7] += __uint_as_float((pv).w & 0xffff0000u); } while (0)

__global__ __launch_bounds__(256) void agg1_gemm2(const __hip_bfloat16* __restrict__ t1,
                                                  const int* __restrict__ row_ptr,
                                                  const int* __restrict__ col,
                                                  const float* __restrict__ dinv,
                                                  const float* __restrict__ b1,
                                                  const float* __restrict__ W2,
                                                  __hip_bfloat16* __restrict__ t2, int n) {
    __shared__ float2 w2p[32 * 40];   // [k/2][c] float2 = {W2[2k'][c], W2[2k'+1][c]}
    for (int i = threadIdx.x; i < 32 * 40; i += 256) {
        int k2 = i / 40, c = i - k2 * 40;
        w2p[i] = make_float2(W2[(2 * k2) * 40 + c], W2[(2 * k2 + 1) * 40 + c]);
    }
    __syncthreads();

    int wave = threadIdx.x >> 6;
    int lane = threadIdx.x & 63;
    int node0 = blockIdx.x * 4 + wave;
    int node = (node0 < n) ? node0 : n - 1;   // clamp; store masked at end
    int r = lane & 7;                          // 16B chunk within row (feats 8r..8r+7)
    int slot = lane >> 3;                      // edge slot within 8-edge group

    const uint4* t1q = (const uint4*)t1;       // row = 8 uint4
    int s0 = row_ptr[node], s1 = row_ptr[node + 1];

    float acc[8] = {0.f, 0.f, 0.f, 0.f, 0.f, 0.f, 0.f, 0.f};

    // self loop: slot 0 only (r == lane for lane < 8)
    if (lane < 8) {
        uint4 pv = t1q[(size_t)node * 8 + lane];
        UNPACK_ADD(pv);
    }

    int bpbase = slot * 4;                     // bpermute byte index base
    for (int jb = s0; jb < s1; jb += 32) {
        int rem = s1 - jb;
        int ll = lane & 31;
        int cidx = col[jb + ((ll < rem) ? ll : 0)];
        int srcg[4];
        #pragma unroll
        for (int g = 0; g < 4; g++) {
            int src = __builtin_amdgcn_ds_bpermute(bpbase + 32 * g, cidx);
            srcg[g] = (8 * g + slot < rem) ? src : n;   // sentinel -> zero row
        }
        uint4 pv[4];
        #pragma unroll
        for (int g = 0; g < 4; g++) pv[g] = t1q[(size_t)srcg[g] * 8 + r];
        #pragma unroll
        for (int g = 0; g < 4; g++) { UNPACK_ADD(pv[g]); }
    }

    // cross-slot butterfly: every lane ends with full sums for feats 8r..8r+7
    #pragma unroll
    for (int off = 8; off < 64; off <<= 1) {
        #pragma unroll
        for (int j = 0; j < 8; j++) acc[j] += __shfl_xor(acc[j], off, 64);
    }

    float dn = dinv[node];
    const float4* b1q = (const float4*)b1;
    float4 ba = b1q[2 * r];
    float4 bb = b1q[2 * r + 1];
    float hv[8];
    hv[0] = fmaxf(0.f, dn * acc[0] + ba.x);
    hv[1] = fmaxf(0.f, dn * acc[1] + ba.y);
    hv[2] = fmaxf(0.f, dn * acc[2] + ba.z);
    hv[3] = fmaxf(0.f, dn * acc[3] + ba.w);
    hv[4] = fmaxf(0.f, dn * acc[4] + bb.x);
    hv[5] = fmaxf(0.f, dn * acc[5] + bb.y);
    hv[6] = fmaxf(0.f, dn * acc[6] + bb.z);
    hv[7] = fmaxf(0.f, dn * acc[7] + bb.w);

    int c = (lane < 40) ? lane : 39;
    float o = 0.0f;
    #pragma unroll
    for (int rr = 0; rr < 8; rr++) {
        #pragma unroll
        for (int j2 = 0; j2 < 4; j2++) {
            float ha = rl_f(hv[2 * j2],     rr);   // h[8rr + 2j2]
            float hb = rl_f(hv[2 * j2 + 1], rr);   // h[8rr + 2j2+1]
            float2 wv = w2p[(4 * rr + j2) * 40 + c];
            o += ha * wv.x + hb * wv.y;
        }
    }
    if (node0 < n && lane < 40)
        t2[(size_t)node * T2STRIDE + lane] = __float2bfloat16(dn * o);
}

// ---------------- agg2 + bias + softmax ----------------
// t2 rows padded to 128B: each random gather touches exactly 1 cache line
// (was 1.625 lines for 80B rows -> ~30% less L2-miss traffic).

__global__ __launch_bounds__(256) void agg2_softmax(const __hip_bfloat16* __restrict__ t2,
                                                    const int* __restrict__ row_ptr,
                                                    const int* __restrict__ col,
                                                    const float* __restrict__ dinv,
                                                    const float* __restrict__ b2,
                                                    float* __restrict__ out, int n) {
    int wave = threadIdx.x >> 6;
    int lane = threadIdx.x & 63;
    int node = blockIdx.x * 4 + wave;
    if (node >= n) return;
    int h = lane >> 5;                 // which edge of the pair
    int p = lane & 31;                 // class-pair index
    int pc = (p < 20) ? p : 19;        // clamped (lanes 20-31 dead weight)
    const unsigned* t2d = (const unsigned*)t2;   // padded row = 32 dwords
    int s0 = row_ptr[node], s1 = row_ptr[node + 1];

    float ax = 0.f, ay = 0.f;
    if (h == 0) {                      // self loop counted once
        unsigned v = t2d[(size_t)node * 32 + pc];
        ax = __uint_as_float(v << 16);
        ay = __uint_as_float(v & 0xffff0000u);
    }
    for (int jb = s0; jb < s1; jb += 16) {
        int rem = s1 - jb;
        int cv = col[jb + ((lane < rem) ? lane : 0)];
        int srcg[8];
        #pragma unroll
        for (int i = 0; i < 8; i++) {
            int eid = 2 * i + h;
            int src = __builtin_amdgcn_ds_bpermute(4 * eid, cv);
            srcg[i] = (eid < rem) ? src : n;           // sentinel -> zero row
        }
        unsigned pv[8];
        #pragma unroll
        for (int i = 0; i < 8; i++) pv[i] = t2d[(size_t)srcg[i] * 32 + pc];
        #pragma unroll
        for (int i = 0; i < 8; i++) {
            ax += __uint_as_float(pv[i] << 16);
            ay += __uint_as_float(pv[i] & 0xffff0000u);
        }
    }
    ax += __shfl_xor(ax, 32, 64);
    ay += __shfl_xor(ay, 32, 64);

    float dn = dinv[node];
    float2 bv = *(const float2*)(b2 + 2 * pc);
    float lx = dn * ax + bv.x;
    float ly = dn * ay + bv.y;
    float m = (p < 20) ? fmaxf(lx, ly) : -INFINITY;
    #pragma unroll
    for (int off = 16; off; off >>= 1) m = fmaxf(m, __shfl_xor(m, off, 64));
    float ex = (p < 20) ? expf(lx - m) : 0.0f;
    float ey = (p < 20) ? expf(ly - m) : 0.0f;
    float ssum = ex + ey;
    #pragma unroll
    for (int off = 16; off; off >>= 1) ssum += __shfl_xor(ssum, off, 64);
    if (h == 0 && p < 20) {
        *(float2*)(out + (size_t)node * NCLS + 2 * p) = make_float2(ex / ssum, ey / ssum);
    }
}

// ---------------- launch ----------------

static inline size_t align256(size_t x) { return (x + 255) & ~(size_t)255; }

extern "C" void kernel_launch(void* const* d_in, const int* in_sizes, int n_in,
                              void* d_out, int out_size, void* d_ws, size_t ws_size,
                              hipStream_t stream) {
    const float* x  = (const float*)d_in[0];
    const int*   ei = (const int*)d_in[1];
    const float* W1 = (const float*)d_in[2];
    const float* b1 = (const float*)d_in[3];
    const float* W2 = (const float*)d_in[4];
    const float* b2 = (const float*)d_in[5];
    float* out = (float*)d_out;

    const int n = in_sizes[0] / NFEAT;      // 100000
    const int e = in_sizes[1] / 2;          // 3200000
    const int nbuckets = (n + BSIZE - 1) >> BSHIFT;   // 196

    char* ws = (char*)d_ws;
    size_t off = 0;
    int*   row_ptr  = (int*)(ws + off);   off += align256((size_t)(n + 1) * 4);
    float* dinv     = (float*)(ws + off); off += align256((size_t)n * 4);
    int*   bcursor  = (int*)(ws + off);   off += align256(256 * 4);
    int*   col      = (int*)(ws + off);   off += align256((size_t)e * 4);
    int*   stage    = (int*)(ws + off);   off += align256((size_t)nbuckets * BCAP * 4);
    unsigned short* w1bt = (unsigned short*)(ws + off); off += align256((size_t)HID * NFEAT * 2);
    __hip_bfloat16* t1 = (__hip_bfloat16*)(ws + off); off += align256((size_t)(n + 1) * HID * 2);
    __hip_bfloat16* t2 = (__hip_bfloat16*)(ws + off); off += align256((size_t)(n + 1) * T2STRIDE * 2);

    (void)hipMemsetAsync(bcursor, 0, 256 * 4, stream);
    (void)hipMemsetAsync(t1 + (size_t)n * HID, 0, HID * 2, stream);          // sentinel zero row
    (void)hipMemsetAsync(t2 + (size_t)n * T2STRIDE, 0, T2STRIDE * 2, stream); // sentinel zero row
    w1_to_bf16t<<<(HID * NFEAT) / 256, 256, 0, stream>>>(W1, w1bt);
    bin_scatter<<<(e + CHUNK - 1) / CHUNK, 256, 0, stream>>>(ei, e, nbuckets, bcursor, stage);
    bucket_csr<<<nbuckets, 256, 0, stream>>>(stage, bcursor, row_ptr, dinv, col, n, e, nbuckets);
    gemm1<<<(n + 63) / 64, 256, 0, stream>>>(x, w1bt, dinv, t1, n);
    agg1_gemm2<<<(n + 3) / 4, 256, 0, stream>>>(t1, row_ptr, col, dinv, b1, W2, t2, n);
    agg2_softmax<<<(n + 3) / 4, 256, 0, stream>>>(t2, row_ptr, col, dinv, b2, out, n);
}